// Round 5
// baseline (488.771 us; speedup 1.0000x reference)
//
#include <hip/hip_runtime.h>

// Problem constants (fixed by the reference)
#define N 2048
#define D 256
#define C 768          // 3*D
#define V 2
#define L 16
#define NSTATE 15      // S_0..S_14 (step-15 mask provably empty)
#define NAPP 14        // encoder applications
#define TCAP 256       // masked-entry cap per variant (expected ~107, 16 sigma)
#define FCAP 64        // follower cap per step (expected ~32, ~6 sigma)

typedef __attribute__((ext_vector_type(8))) short bf16x8;
typedef __attribute__((ext_vector_type(4))) float f32x4;

__device__ __forceinline__ ushort bf16_rn(float x) {
  unsigned u = __float_as_uint(x);
  u += 0x7FFFu + ((u >> 16) & 1u);
  return (ushort)(u >> 16);
}
__device__ __forceinline__ float bf16_f(ushort h) {
  return __uint_as_float(((unsigned)h) << 16);
}

// Chunk-tiled operand layouts (chunk = 32 rows x 64 k = 2048 ushorts = 4 KB
// contiguous).  A: row in [0,2048), k in [0,256).
__device__ __forceinline__ size_t a_addr(int row, int k) {
  return ((size_t)(row >> 5) * 4 + (k >> 6)) * 2048 + (row & 31) * 64 + (k & 63);
}
// W^T: n in [0,512), k in [0,256).
__device__ __forceinline__ size_t wt_addr(int n, int k) {
  return ((size_t)(n >> 5) * 4 + (k >> 6)) * 2048 + (n & 31) * 64 + (k & 63);
}

// ---------------------------------------------------------------------------
// k_init: states0 = emb; A0 bf16 split (chunked); Wt=[W_self|W_nbr]^T split
// (chunked); zero out.
// ---------------------------------------------------------------------------
__global__ __launch_bounds__(256) void k_init(
    const float* __restrict__ emb, const float* __restrict__ Ws,
    const float* __restrict__ Wn, float* __restrict__ states0,
    ushort* __restrict__ WtHi, ushort* __restrict__ WtLo,
    ushort* __restrict__ A0hi, ushort* __restrict__ A0lo,
    float* __restrict__ out) {
  size_t i = (size_t)blockIdx.x * 256 + threadIdx.x;
  size_t stride = (size_t)gridDim.x * 256;
  for (size_t x = i; x < (size_t)N * D; x += stride) {
    float v = emb[x];
    states0[x] = v;
    ushort h = bf16_rn(v);
    ushort l = bf16_rn(v - bf16_f(h));
    size_t a = a_addr((int)(x >> 8), (int)(x & 255));
    A0hi[a] = h;
    A0lo[a] = l;
  }
  for (size_t x = i; x < (size_t)512 * 256; x += stride) {
    int n = (int)(x >> 8), k = (int)(x & 255);
    float v = (n < 256) ? Ws[(size_t)k * 256 + n] : Wn[(size_t)k * 256 + (n - 256)];
    ushort h = bf16_rn(v);
    size_t a = wt_addr(n, k);
    WtHi[a] = h;
    WtLo[a] = bf16_rn(v - bf16_f(h));
  }
  for (size_t x = i; x < (size_t)N * C; x += stride) out[x] = 0.f;
}

// ---------------------------------------------------------------------------
// k_csr: full CSR build (by dst, keeps multiplicity) in ONE single-block
// kernel: LDS degree count -> shuffle scan -> fill.  ei[0..E)=src, [E..2E)=dst.
// ---------------------------------------------------------------------------
__global__ __launch_bounds__(1024) void k_csr(
    const int* __restrict__ ei, int E, int* __restrict__ row_ptr,
    int* __restrict__ csr_src) {
  __shared__ int deg[N];
  __shared__ int fpos[N];
  __shared__ int wsum[16];
  int t = threadIdx.x;
  deg[t] = 0;
  deg[t + 1024] = 0;
  __syncthreads();
  for (int e = t; e < E; e += 1024) atomicAdd(&deg[ei[E + e]], 1);
  __syncthreads();
  int d0 = deg[2 * t], d1 = deg[2 * t + 1];
  int s = d0 + d1;
  int lane = t & 63, wave = t >> 6;
  for (int off = 1; off < 64; off <<= 1) {
    int vsh = __shfl_up(s, off, 64);
    if (lane >= off) s += vsh;
  }
  if (lane == 63) wsum[wave] = s;
  __syncthreads();
  int wbase = 0;
  for (int w = 0; w < wave; w++) wbase += wsum[w];
  int base = wbase + s - d0 - d1;   // exclusive prefix
  row_ptr[2 * t] = base;
  row_ptr[2 * t + 1] = base + d0;
  fpos[2 * t] = base;
  fpos[2 * t + 1] = base + d0;
  if (t == 1023) row_ptr[N] = base + d0 + d1;
  __syncthreads();
  for (int e = t; e < E; e += 1024) {
    int dst = ei[E + e];
    int pos = atomicAdd(&fpos[dst], 1);
    csr_src[pos] = ei[e];
  }
}

// ---------------------------------------------------------------------------
// k_meta2: one block per variant.  Emits, per variant:
//   entries (place, dmask, prev-entry-of-same-place) grouped by step (offs),
//   per-step tl list + kidx (state index), last-entry list (place, idx,
//   step-membership mask) and cmat[i][j] = |M_i ∩ M_j|.
// Follower x suffix checks parallelized over pairs (no serial 15-chain).
// ---------------------------------------------------------------------------
__global__ __launch_bounds__(256) void k_meta2(
    const int* __restrict__ adj, const int* __restrict__ variants,
    int* __restrict__ entP, int* __restrict__ entPrev, int* __restrict__ entDm,
    int* __restrict__ offsG, int* __restrict__ kidxG, int* __restrict__ tlG,
    int* __restrict__ cmatG, int* __restrict__ lastPG, int* __restrict__ lastIG,
    int* __restrict__ lastMG, int* __restrict__ cntG) {
  __shared__ int pmask[N];
  __shared__ int lastE[N];
  __shared__ int tl_sh[16];
  __shared__ int foll[FCAP], fbits[FCAP];
  __shared__ int sh_tc, sh_a, sh_fcnt, sh_cnt, sh_u;
  __shared__ int offs_sh[17], has_sh[16];
  __shared__ int cmat_sh[256];
  int v = blockIdx.x, t = threadIdx.x;
  for (int p = t; p < N; p += 256) { pmask[p] = 0; lastE[p] = -1; }
  for (int x = t; x < 256; x += 256) cmat_sh[x] = 0;
  if (t == 0) { sh_cnt = 0; sh_u = 0; }
  __syncthreads();
  for (int i = 0; i < L; i++) {
    if (t == 0) {
      int a = variants[v * L + i];
      sh_a = a;
      int cnt = 0;
      for (int j = i + 1; j < L; j++) {
        int x = variants[v * L + j];
        bool dup = false;
        for (int q = 0; q < cnt; q++) if (tl_sh[q] == x) dup = true;
        if (!dup) tl_sh[cnt++] = x;
      }
      sh_tc = cnt;
      sh_fcnt = 0;
      offs_sh[i] = sh_cnt < TCAP ? sh_cnt : TCAP;
      for (int q = 0; q < cnt; q++) tlG[(v * 16 + i) * 16 + q] = tl_sh[q];
    }
    __syncthreads();
    int a = sh_a;
    for (int p = t; p < N; p += 256) {
      if (adj[(size_t)a * N + p] != 0) {
        int f = atomicAdd(&sh_fcnt, 1);
        if (f < FCAP) foll[f] = p;
      }
    }
    __syncthreads();
    int fc = sh_fcnt < FCAP ? sh_fcnt : FCAP;
    int tc = sh_tc;
    for (int x = t; x < fc; x += 256) fbits[x] = 0;
    __syncthreads();
    for (int x = t; x < fc * tc; x += 256) {
      int fi = x / tc, q = x - fi * tc;
      if (adj[(size_t)foll[fi] * N + tl_sh[q]] != 0) atomicOr(&fbits[fi], 1 << q);
    }
    __syncthreads();
    for (int fi = t; fi < fc; fi += 256) {
      int bits = fbits[fi];
      if (bits) {
        int e = atomicAdd(&sh_cnt, 1);
        if (e < TCAP) {
          int p = foll[fi];
          entP[v * TCAP + e] = p;
          entDm[v * TCAP + e] = bits;
          entPrev[v * TCAP + e] = lastE[p];
          lastE[p] = e;
          pmask[p] |= 1 << i;
        }
      }
    }
    __syncthreads();
    if (t == 0) has_sh[i] = (sh_fcnt > 0);
    __syncthreads();
  }
  if (t == 0) {
    offs_sh[16] = sh_cnt < TCAP ? sh_cnt : TCAP;
    int k = 0;
    for (int i = 0; i < L; i++) { kidxG[v * 16 + i] = k; if (has_sh[i]) k++; }
    for (int i = 0; i <= 16; i++) offsG[v * 17 + i] = offs_sh[i];
    cntG[v * 2 + 0] = offs_sh[16];
  }
  __syncthreads();
  for (int p = t; p < N; p += 256) {
    if (lastE[p] >= 0) {
      int u = atomicAdd(&sh_u, 1);
      lastPG[v * TCAP + u] = p;
      lastIG[v * TCAP + u] = lastE[p];
      lastMG[v * TCAP + u] = pmask[p];
      int m = pmask[p], mm = m;
      while (mm) {
        int bi = __ffs(mm) - 1; mm &= mm - 1;
        int m2 = m & ((1 << bi) - 1);
        while (m2) {
          int bj = __ffs(m2) - 1; m2 &= m2 - 1;
          atomicAdd(&cmat_sh[bi * 16 + bj], 1);
        }
      }
    }
  }
  __syncthreads();
  if (t == 0) cntG[v * 2 + 1] = sh_u;
  for (int x = t; x < 256; x += 256) cmatG[v * 256 + x] = cmat_sh[x];
}

// ---------------------------------------------------------------------------
// k_gemm: Z = A @ [W_self|W_nbr]  (M=2048, K=256, N=512), bf16 3-product
// split, fp32 accum.  Grid (64,16); block tile 32x32, 4 waves 2x2 of 16x16
// mfma tiles.  Chunked operands: staged chunk = contiguous 4 KB; register
// prefetch of chunk c+1 overlaps MFMA of chunk c.  (validated R2/R4)
// ---------------------------------------------------------------------------
__global__ __launch_bounds__(256) void k_gemm(
    const ushort* __restrict__ Ah, const ushort* __restrict__ Al,
    const ushort* __restrict__ Wh_g, const ushort* __restrict__ Wl_g,
    float* __restrict__ Z) {
  __shared__ __align__(16) ushort Ash[32][72], Asl[32][72];
  __shared__ __align__(16) ushort Wsh[32][72], Wsl[32][72];
  const int tid = threadIdx.x, wave = tid >> 6, lane = tid & 63;
  const int quad = lane >> 4, l16 = lane & 15;
  const int wr = wave >> 1, wc = wave & 1;
  const int mb = blockIdx.x, nb = blockIdx.y;
  const int sr = tid >> 3, sc = (tid & 7) * 8;

  f32x4 acc = {0.f, 0.f, 0.f, 0.f};
  size_t abase = (size_t)mb * 4 * 2048 + (size_t)tid * 8;
  size_t wbase = (size_t)nb * 4 * 2048 + (size_t)tid * 8;
  uint4 ra  = *(const uint4*)&Ah[abase];
  uint4 rl  = *(const uint4*)&Al[abase];
  uint4 rwh = *(const uint4*)&Wh_g[wbase];
  uint4 rwl = *(const uint4*)&Wl_g[wbase];
#pragma unroll
  for (int c = 0; c < 4; c++) {
    *(uint4*)&Ash[sr][sc] = ra;
    *(uint4*)&Asl[sr][sc] = rl;
    *(uint4*)&Wsh[sr][sc] = rwh;
    *(uint4*)&Wsl[sr][sc] = rwl;
    __syncthreads();
    if (c < 3) {
      size_t o = (size_t)(c + 1) * 2048;
      ra  = *(const uint4*)&Ah[abase + o];
      rl  = *(const uint4*)&Al[abase + o];
      rwh = *(const uint4*)&Wh_g[wbase + o];
      rwl = *(const uint4*)&Wl_g[wbase + o];
    }
#pragma unroll
    for (int kf = 0; kf < 2; kf++) {
      int ko = kf * 32 + quad * 8;
      bf16x8 a_h = *(const bf16x8*)&Ash[wr * 16 + l16][ko];
      bf16x8 a_l = *(const bf16x8*)&Asl[wr * 16 + l16][ko];
      bf16x8 w_h = *(const bf16x8*)&Wsh[wc * 16 + l16][ko];
      bf16x8 w_l = *(const bf16x8*)&Wsl[wc * 16 + l16][ko];
      acc = __builtin_amdgcn_mfma_f32_16x16x32_bf16(a_h, w_h, acc, 0, 0, 0);
      acc = __builtin_amdgcn_mfma_f32_16x16x32_bf16(a_h, w_l, acc, 0, 0, 0);
      acc = __builtin_amdgcn_mfma_f32_16x16x32_bf16(a_l, w_h, acc, 0, 0, 0);
    }
    __syncthreads();
  }
  int col = nb * 32 + wc * 16 + l16;
  int row0 = mb * 32 + wr * 16 + quad * 4;
#pragma unroll
  for (int r = 0; r < 4; r++)
    Z[(size_t)(row0 + r) * 512 + col] = acc[r];
}

// ---------------------------------------------------------------------------
// k_comb: next[r] = relu(Z1[r] + sum_{e in in(r)} Z2[src_e] + b).  2 waves
// per row split the edge list (halves the serial gather chain); LDS combine.
// Writes states fp32 + bf16 split of next A (chunked layout).
// ---------------------------------------------------------------------------
__global__ __launch_bounds__(256) void k_comb(
    const float* __restrict__ Z, const float* __restrict__ bias,
    const int* __restrict__ row_ptr, const int* __restrict__ csr_src,
    float* __restrict__ stnext, ushort* __restrict__ NAh,
    ushort* __restrict__ NAl) {
  __shared__ float4 part[2][64];
  int wid = threadIdx.x >> 6, lane = threadIdx.x & 63;
  int rp = wid >> 1, half = wid & 1;
  int row = blockIdx.x * 2 + rp;
  int e0 = row_ptr[row], e1 = row_ptr[row + 1];
  int mid = (e0 + e1 + 1) >> 1;
  int lo = half ? mid : e0, hi = half ? e1 : mid;
  float4 acc = {0.f, 0.f, 0.f, 0.f};
  for (int e = lo; e < hi; e++) {
    const float4* z2 = (const float4*)(Z + (size_t)csr_src[e] * 512 + 256);
    float4 x = z2[lane];
    acc.x += x.x; acc.y += x.y; acc.z += x.z; acc.w += x.w;
  }
  if (half) part[rp][lane] = acc;
  __syncthreads();
  if (!half) {
    float4 o = part[rp][lane];
    float4 zs = ((const float4*)(Z + (size_t)row * 512))[lane];
    float4 bv = ((const float4*)bias)[lane];
    float v0 = fmaxf(acc.x + o.x + zs.x + bv.x, 0.f);
    float v1 = fmaxf(acc.y + o.y + zs.y + bv.y, 0.f);
    float v2 = fmaxf(acc.z + o.z + zs.z + bv.z, 0.f);
    float v3 = fmaxf(acc.w + o.w + zs.w + bv.w, 0.f);
    *(float4*)(stnext + (size_t)row * D + lane * 4) = make_float4(v0, v1, v2, v3);
    ushort h0 = bf16_rn(v0), h1 = bf16_rn(v1), h2 = bf16_rn(v2), h3 = bf16_rn(v3);
    size_t ca = a_addr(row, lane * 4);
    *(ushort4*)&NAh[ca] = make_ushort4(h0, h1, h2, h3);
    *(ushort4*)&NAl[ca] = make_ushort4(
        bf16_rn(v0 - bf16_f(h0)), bf16_rn(v1 - bf16_f(h1)),
        bf16_rn(v2 - bf16_f(h2)), bf16_rn(v3 - bf16_f(h3)));
  }
}

// ---------------------------------------------------------------------------
// k_pi: LINEAR reformulation of the pi/summary recurrence (no serial
// global/LDS RMW chain).  Per column c:
//   pref[e] = cat[e] + pref[prev(e)]                  (per-slot prefix)
//   S_i = S_{i-1} + sum_{e in step i} pref[e] + sum_{j<i} cmat[i][j]*S_j
//   out[p] += pref[last(p)] + sum_{i in pmask(p)} S_i
// Grid V*12 blocks x 64 threads (64 cols each); atomicAdd into zeroed d_out.
// ---------------------------------------------------------------------------
#define PI_LDS_BYTES (TCAP * 64 * 4 + 16 * 64 * 4 + 3 * TCAP * 4 + 17 * 4 + 16 * 4 + 256 * 4)
__global__ __launch_bounds__(64) void k_pi(
    const float* __restrict__ states, float* __restrict__ out,
    const int* __restrict__ variants,
    const int* __restrict__ entP, const int* __restrict__ entPrev,
    const int* __restrict__ entDm, const int* __restrict__ offsG,
    const int* __restrict__ kidxG, const int* __restrict__ tlG,
    const int* __restrict__ cmatG, const int* __restrict__ lastPG,
    const int* __restrict__ lastIG, const int* __restrict__ lastMG,
    const int* __restrict__ cntG) {
  extern __shared__ __align__(16) float smf[];
  float* catb = smf;                       // [TCAP][64]  (becomes pref)
  float* S_lds = catb + TCAP * 64;         // [16][64]
  int* eP  = (int*)(S_lds + 16 * 64);      // [TCAP]
  int* ePr = eP + TCAP;
  int* eDm = ePr + TCAP;
  int* offs = eDm + TCAP;                  // [17]
  int* kidx = offs + 17;                   // [16]
  int* tl = kidx + 16;                     // [256]
  int v = blockIdx.x / 12, cgi = blockIdx.x % 12;
  int grp = cgi >> 2;
  int lane = threadIdx.x;
  int cl = (cgi & 3) * 64 + lane;          // 0..255 within third
  int col = cgi * 64 + lane;               // 0..767

  int T = cntG[v * 2 + 0], U = cntG[v * 2 + 1];
  for (int x = lane; x < T; x += 64) {
    eP[x] = entP[v * TCAP + x];
    ePr[x] = entPrev[v * TCAP + x];
    eDm[x] = entDm[v * TCAP + x];
  }
  for (int x = lane; x < 17; x += 64) offs[x] = offsG[v * 17 + x];
  if (lane < 16) kidx[lane] = kidxG[v * 16 + lane];
  for (int x = lane; x < 256; x += 64) tl[x] = tlG[v * 256 + x];
  __syncthreads();

  // Phase 1: gather cat values (independent loads, MLP-pipelined)
  for (int i = 0; i < L; i++) {
    int kk = kidx[i]; if (kk > NSTATE - 1) kk = NSTATE - 1;
    const float* embS = states + (size_t)kk * N * D;
    int o0 = offs[i], o1 = offs[i + 1];
    if (grp == 0) {
      for (int e = o0; e < o1; e++)
        catb[e * 64 + lane] = embS[(size_t)eP[e] * D + cl];
    } else if (grp == 1) {
      float embA = embS[(size_t)variants[v * L + i] * D + cl];
      for (int e = o0; e < o1; e++) catb[e * 64 + lane] = embA;
    } else {
      for (int e = o0; e < o1; e++) {
        float s = 0.f;
        int b = eDm[e];
        while (b) {
          int q = __ffs(b) - 1; b &= b - 1;
          s += embS[(size_t)tl[i * 16 + q] * D + cl];
        }
        catb[e * 64 + lane] = s;
      }
    }
  }
  // Phase 2: in-place per-slot prefix (prev < e, ascending order)
  for (int e = 0; e < T; e++) {
    int pr = ePr[e];
    if (pr >= 0) catb[e * 64 + lane] += catb[pr * 64 + lane];
  }
  // Phase 3: 16-step S recurrence (registers, static unroll)
  float S[16];
  float Sp = 0.f;
#pragma unroll
  for (int i = 0; i < 16; i++) {
    float a = 0.f;
    for (int e = offs[i]; e < offs[i + 1]; e++) a += catb[e * 64 + lane];
    float s = Sp + a;
#pragma unroll
    for (int j = 0; j < 16; j++)
      if (j < i) s += (float)cmatG[v * 256 + i * 16 + j] * S[j];
    S[i] = s;
    S_lds[i * 64 + lane] = s;
    Sp = s;
  }
  // Phase 4: one atomic per (union place, col)
  for (int u = 0; u < U; u++) {
    int p = lastPG[v * TCAP + u];
    int li = lastIG[v * TCAP + u];
    int m = lastMG[v * TCAP + u];
    float acc = catb[li * 64 + lane];
    while (m) {
      int q = __ffs(m) - 1; m &= m - 1;
      acc += S_lds[q * 64 + lane];
    }
    atomicAdd(&out[(size_t)p * C + col], acc);
  }
}

// ---------------------------------------------------------------------------
extern "C" void kernel_launch(void* const* d_in, const int* in_sizes, int n_in,
                              void* d_out, int out_size, void* d_ws, size_t ws_size,
                              hipStream_t stream) {
  const float* emb      = (const float*)d_in[0];
  const float* Ws       = (const float*)d_in[1];
  const float* Wn       = (const float*)d_in[2];
  const float* bias     = (const float*)d_in[3];
  const int*   variants = (const int*)d_in[4];
  const int*   adj      = (const int*)d_in[5];
  const int*   ei       = (const int*)d_in[6];
  const int    E        = in_sizes[6] / 2;
  float* out            = (float*)d_out;

  char* base = (char*)d_ws;
  float* states = (float*)base;            base += (size_t)NSTATE * N * D * 4;
  float* Z      = (float*)base;            base += (size_t)N * 512 * 4;
  ushort* WtHi  = (ushort*)base;           base += (size_t)512 * 256 * 2;
  ushort* WtLo  = (ushort*)base;           base += (size_t)512 * 256 * 2;
  ushort* A0h   = (ushort*)base;           base += (size_t)N * D * 2;
  ushort* A0l   = (ushort*)base;           base += (size_t)N * D * 2;
  ushort* A1h   = (ushort*)base;           base += (size_t)N * D * 2;
  ushort* A1l   = (ushort*)base;           base += (size_t)N * D * 2;
  int* row_ptr  = (int*)base;              base += (N + 1) * 4;
  int* csr_src  = (int*)base;              base += (size_t)E * 4;
  int* entP     = (int*)base;              base += V * TCAP * 4;
  int* entPrev  = (int*)base;              base += V * TCAP * 4;
  int* entDm    = (int*)base;              base += V * TCAP * 4;
  int* offsG    = (int*)base;              base += V * 17 * 4;
  int* kidxG    = (int*)base;              base += V * 16 * 4;
  int* tlG      = (int*)base;              base += V * 256 * 4;
  int* cmatG    = (int*)base;              base += V * 256 * 4;
  int* lastPG   = (int*)base;              base += V * TCAP * 4;
  int* lastIG   = (int*)base;              base += V * TCAP * 4;
  int* lastMG   = (int*)base;              base += V * TCAP * 4;
  int* cntG     = (int*)base;              base += V * 2 * 4;

  hipFuncSetAttribute((const void*)k_pi,
                      hipFuncAttributeMaxDynamicSharedMemorySize, PI_LDS_BYTES);

  k_init<<<512, 256, 0, stream>>>(emb, Ws, Wn, states, WtHi, WtLo, A0h, A0l, out);
  k_csr<<<1, 1024, 0, stream>>>(ei, E, row_ptr, csr_src);
  k_meta2<<<V, 256, 0, stream>>>(adj, variants, entP, entPrev, entDm, offsG,
                                 kidxG, tlG, cmatG, lastPG, lastIG, lastMG, cntG);

  ushort* AH[2] = {A0h, A1h};
  ushort* AL[2] = {A0l, A1l};
  for (int s = 0; s < NAPP; s++) {
    int cur = s & 1, nxt = cur ^ 1;
    k_gemm<<<dim3(64, 16), 256, 0, stream>>>(AH[cur], AL[cur], WtHi, WtLo, Z);
    k_comb<<<N / 2, 256, 0, stream>>>(Z, bias, row_ptr, csr_src,
                                      states + (size_t)(s + 1) * N * D,
                                      AH[nxt], AL[nxt]);
  }
  k_pi<<<V * 12, 64, PI_LDS_BYTES, stream>>>(states, out, variants, entP,
                                             entPrev, entDm, offsG, kidxG, tlG,
                                             cmatG, lastPG, lastIG, lastMG, cntG);
}

// Round 6
// 386.876 us; speedup vs baseline: 1.2634x; 1.2634x over previous
//
#include <hip/hip_runtime.h>

// Problem constants (fixed by the reference)
#define N 2048
#define D 256
#define C 768          // 3*D
#define V 2
#define L 16
#define NSTATE 15      // S_0..S_14 (step-15 mask provably empty)
#define NAPP 14        // encoder applications
#define TCAP 256       // canonical masked-entry cap per variant (expected ~107)
#define FCAP 64        // follower cap per step (expected ~32)

typedef __attribute__((ext_vector_type(8))) short bf16x8;
typedef __attribute__((ext_vector_type(4))) float f32x4;

__device__ __forceinline__ ushort bf16_rn(float x) {
  unsigned u = __float_as_uint(x);
  u += 0x7FFFu + ((u >> 16) & 1u);
  return (ushort)(u >> 16);
}
__device__ __forceinline__ float bf16_f(ushort h) {
  return __uint_as_float(((unsigned)h) << 16);
}

// Chunk-tiled operand layouts (chunk = 32 rows x 64 k = 2048 ushorts = 4 KB).
__device__ __forceinline__ size_t a_addr(int row, int k) {
  return ((size_t)(row >> 5) * 4 + (k >> 6)) * 2048 + (row & 31) * 64 + (k & 63);
}
__device__ __forceinline__ size_t wt_addr(int n, int k) {
  return ((size_t)(n >> 5) * 4 + (k >> 6)) * 2048 + (n & 31) * 64 + (k & 63);
}

// ---------------------------------------------------------------------------
// k_init: states0 = emb; A0 bf16 split (chunked); Wt=[W_self|W_nbr]^T split
// (chunked); zero out / fillpos.
// ---------------------------------------------------------------------------
__global__ __launch_bounds__(256) void k_init(
    const float* __restrict__ emb, const float* __restrict__ Ws,
    const float* __restrict__ Wn, float* __restrict__ states0,
    ushort* __restrict__ WtHi, ushort* __restrict__ WtLo,
    ushort* __restrict__ A0hi, ushort* __restrict__ A0lo,
    float* __restrict__ out, int* __restrict__ fillpos) {
  size_t i = (size_t)blockIdx.x * 256 + threadIdx.x;
  size_t stride = (size_t)gridDim.x * 256;
  for (size_t x = i; x < (size_t)N * D; x += stride) {
    float v = emb[x];
    states0[x] = v;
    ushort h = bf16_rn(v);
    ushort l = bf16_rn(v - bf16_f(h));
    size_t a = a_addr((int)(x >> 8), (int)(x & 255));
    A0hi[a] = h;
    A0lo[a] = l;
  }
  for (size_t x = i; x < (size_t)512 * 256; x += stride) {
    int n = (int)(x >> 8), k = (int)(x & 255);
    float v = (n < 256) ? Ws[(size_t)k * 256 + n] : Wn[(size_t)k * 256 + (n - 256)];
    ushort h = bf16_rn(v);
    size_t a = wt_addr(n, k);
    WtHi[a] = h;
    WtLo[a] = bf16_rn(v - bf16_f(h));
  }
  for (size_t x = i; x < (size_t)N * C; x += stride) out[x] = 0.f;
  for (size_t x = i; x < N; x += stride) fillpos[x] = 0;
}

// ---------------------------------------------------------------------------
// CSR build (by dst, keeps multiplicity) — proven 3-kernel version (R2/R4).
// ---------------------------------------------------------------------------
__global__ void k_deg(const int* __restrict__ ei, int* __restrict__ fillpos, int E) {
  int e = blockIdx.x * 256 + threadIdx.x;
  if (e < E) atomicAdd(&fillpos[ei[E + e]], 1);
}

__global__ __launch_bounds__(256) void k_scan(int* __restrict__ fillpos,
                                              int* __restrict__ row_ptr) {
  __shared__ int part[256];
  __shared__ int base[257];
  int t = threadIdx.x;
  int v[8];
  int s = 0;
  for (int j = 0; j < 8; j++) { v[j] = fillpos[t * 8 + j]; s += v[j]; }
  part[t] = s;
  __syncthreads();
  if (t == 0) {
    int acc = 0;
    for (int q = 0; q < 256; q++) { base[q] = acc; acc += part[q]; }
    base[256] = acc;
  }
  __syncthreads();
  int acc = base[t];
  for (int j = 0; j < 8; j++) {
    row_ptr[t * 8 + j] = acc;
    fillpos[t * 8 + j] = acc;
    acc += v[j];
  }
  if (t == 255) row_ptr[N] = base[256];
}

__global__ void k_fill(const int* __restrict__ ei, int* __restrict__ fillpos,
                       int* __restrict__ csr_src, int E) {
  int e = blockIdx.x * 256 + threadIdx.x;
  if (e < E) {
    int dst = ei[E + e];
    int pos = atomicAdd(&fillpos[dst], 1);
    csr_src[pos] = ei[e];
  }
}

// ---------------------------------------------------------------------------
// k_metaA: per (variant, step) block — the adj-touching, step-independent
// part.  Emits per-step follower lists with destination bitmasks.
// ---------------------------------------------------------------------------
__global__ __launch_bounds__(256) void k_metaA(
    const int* __restrict__ adj, const int* __restrict__ variants,
    int* __restrict__ stepP, int* __restrict__ stepDm,
    int* __restrict__ stepCnt, int* __restrict__ hasG, int* __restrict__ tlG) {
  __shared__ int tl_sh[16];
  __shared__ int foll[FCAP], fbits[FCAP];
  __shared__ int sh_tc, sh_fcnt, sh_ecnt;
  int vi = blockIdx.x;
  int v = vi / L, i = vi % L;
  int t = threadIdx.x;
  int a = variants[vi];
  if (t == 0) {
    int cnt = 0;
    for (int j = i + 1; j < L; j++) {
      int x = variants[v * L + j];
      bool dup = false;
      for (int q = 0; q < cnt; q++) if (tl_sh[q] == x) dup = true;
      if (!dup) tl_sh[cnt++] = x;
    }
    sh_tc = cnt;
    sh_fcnt = 0;
    sh_ecnt = 0;
    for (int q = 0; q < cnt; q++) tlG[vi * 16 + q] = tl_sh[q];
  }
  __syncthreads();
  for (int p = t; p < N; p += 256) {
    if (adj[(size_t)a * N + p] != 0) {
      int f = atomicAdd(&sh_fcnt, 1);
      if (f < FCAP) foll[f] = p;
    }
  }
  __syncthreads();
  int fc = sh_fcnt < FCAP ? sh_fcnt : FCAP;
  int tc = sh_tc;
  for (int x = t; x < fc; x += 256) fbits[x] = 0;
  __syncthreads();
  for (int x = t; x < fc * tc; x += 256) {
    int fi = x / tc, q = x - fi * tc;
    if (adj[(size_t)foll[fi] * N + tl_sh[q]] != 0) atomicOr(&fbits[fi], 1 << q);
  }
  __syncthreads();
  for (int fi = t; fi < fc; fi += 256) {
    int bits = fbits[fi];
    if (bits) {
      int e = atomicAdd(&sh_ecnt, 1);
      stepP[vi * FCAP + e] = foll[fi];
      stepDm[vi * FCAP + e] = bits;
    }
  }
  __syncthreads();
  if (t == 0) {
    stepCnt[vi] = sh_ecnt;
    hasG[vi] = (sh_fcnt > 0);
  }
}

// ---------------------------------------------------------------------------
// k_metaB: per-variant linking on compacted lists (no adj access).  Builds
// canonical entry arrays (entP/entPrev/entDm + offs), kidx, last-entry lists
// (place/index/step-mask), and cmat[i][j] = |M_i ∩ M_j|.
// ---------------------------------------------------------------------------
__global__ __launch_bounds__(256) void k_metaB(
    const int* __restrict__ stepP, const int* __restrict__ stepDm,
    const int* __restrict__ stepCnt, const int* __restrict__ hasG,
    int* __restrict__ entP, int* __restrict__ entPrev, int* __restrict__ entDm,
    int* __restrict__ offsG, int* __restrict__ kidxG, int* __restrict__ cmatG,
    int* __restrict__ lastPG, int* __restrict__ lastIG, int* __restrict__ lastMG,
    int* __restrict__ cntG) {
  __shared__ int pmask[N];           // 8 KB
  __shared__ int sP[16][FCAP];       // 4 KB
  __shared__ int sDm[16][FCAP];      // 4 KB
  __shared__ int cnt[16], offs[17];
  __shared__ int cmat_sh[256];       // 1 KB
  __shared__ int sh_u;
  int v = blockIdx.x, t = threadIdx.x;
  for (int p = t; p < N; p += 256) pmask[p] = 0;
  for (int x = t; x < 256; x += 256) cmat_sh[x] = 0;
  if (t < 16) cnt[t] = stepCnt[v * L + t];
  if (t == 0) sh_u = 0;
  __syncthreads();
  if (t == 0) {
    int acc = 0;
    for (int i = 0; i < 16; i++) {
      offs[i] = acc < TCAP ? acc : TCAP;
      acc += cnt[i];
    }
    offs[16] = acc < TCAP ? acc : TCAP;
    cntG[v * 2 + 0] = offs[16];
    int k = 0;
    for (int i = 0; i < L; i++) {
      kidxG[v * 16 + i] = k;
      if (hasG[v * L + i]) k++;
    }
  }
  // stage per-step lists + pmask
  for (int x = t; x < 16 * FCAP; x += 256) {
    int i = x >> 6, f = x & 63;
    if (f < stepCnt[v * L + i]) {
      int p = stepP[(v * L + i) * FCAP + f];
      sP[i][f] = p;
      sDm[i][f] = stepDm[(v * L + i) * FCAP + f];
      atomicOr(&pmask[p], 1 << i);
    }
  }
  __syncthreads();
  // canonical entries + prev chains
  for (int x = t; x < 16 * FCAP; x += 256) {
    int i = x >> 6, f = x & 63;
    if (f < cnt[i]) {
      int e = offs[i] + f;
      if (e < TCAP) {
        int p = sP[i][f];
        entP[v * TCAP + e] = p;
        entDm[v * TCAP + e] = sDm[i][f];
        int m = pmask[p] & ((1 << i) - 1);
        int prev = -1;
        if (m) {
          int j = 31 - __clz(m);        // latest earlier step containing p
          int cj = cnt[j];
          for (int f2 = 0; f2 < cj; f2++)
            if (sP[j][f2] == p) { prev = offs[j] + f2; break; }
        }
        entPrev[v * TCAP + e] = prev;
      }
    }
  }
  __syncthreads();
  // union places: last entry + step-mask + cmat
  for (int p = t; p < N; p += 256) {
    int m = pmask[p];
    if (m) {
      int u = atomicAdd(&sh_u, 1);
      int j = 31 - __clz(m);            // last step containing p
      int li = -1;
      int cj = cnt[j];
      for (int f2 = 0; f2 < cj; f2++)
        if (sP[j][f2] == p) { li = offs[j] + f2; break; }
      lastPG[v * TCAP + u] = p;
      lastIG[v * TCAP + u] = li;
      lastMG[v * TCAP + u] = m;
      int mm = m;
      while (mm) {
        int bi = __ffs(mm) - 1; mm &= mm - 1;
        int m2 = m & ((1 << bi) - 1);
        while (m2) {
          int bj = __ffs(m2) - 1; m2 &= m2 - 1;
          atomicAdd(&cmat_sh[bi * 16 + bj], 1);
        }
      }
    }
  }
  __syncthreads();
  if (t == 0) cntG[v * 2 + 1] = sh_u;
  for (int x = t; x < 256; x += 256) cmatG[v * 256 + x] = cmat_sh[x];
  for (int x = t; x < 17; x += 256) offsG[v * 17 + x] = offs[x];
}

// ---------------------------------------------------------------------------
// k_gemm: Z = A @ [W_self|W_nbr]  (M=2048, K=256, N=512), bf16 3-product
// split, fp32 accum.  (validated R2/R4)
// ---------------------------------------------------------------------------
__global__ __launch_bounds__(256) void k_gemm(
    const ushort* __restrict__ Ah, const ushort* __restrict__ Al,
    const ushort* __restrict__ Wh_g, const ushort* __restrict__ Wl_g,
    float* __restrict__ Z) {
  __shared__ __align__(16) ushort Ash[32][72], Asl[32][72];
  __shared__ __align__(16) ushort Wsh[32][72], Wsl[32][72];
  const int tid = threadIdx.x, wave = tid >> 6, lane = tid & 63;
  const int quad = lane >> 4, l16 = lane & 15;
  const int wr = wave >> 1, wc = wave & 1;
  const int mb = blockIdx.x, nb = blockIdx.y;
  const int sr = tid >> 3, sc = (tid & 7) * 8;

  f32x4 acc = {0.f, 0.f, 0.f, 0.f};
  size_t abase = (size_t)mb * 4 * 2048 + (size_t)tid * 8;
  size_t wbase = (size_t)nb * 4 * 2048 + (size_t)tid * 8;
  uint4 ra  = *(const uint4*)&Ah[abase];
  uint4 rl  = *(const uint4*)&Al[abase];
  uint4 rwh = *(const uint4*)&Wh_g[wbase];
  uint4 rwl = *(const uint4*)&Wl_g[wbase];
#pragma unroll
  for (int c = 0; c < 4; c++) {
    *(uint4*)&Ash[sr][sc] = ra;
    *(uint4*)&Asl[sr][sc] = rl;
    *(uint4*)&Wsh[sr][sc] = rwh;
    *(uint4*)&Wsl[sr][sc] = rwl;
    __syncthreads();
    if (c < 3) {
      size_t o = (size_t)(c + 1) * 2048;
      ra  = *(const uint4*)&Ah[abase + o];
      rl  = *(const uint4*)&Al[abase + o];
      rwh = *(const uint4*)&Wh_g[wbase + o];
      rwl = *(const uint4*)&Wl_g[wbase + o];
    }
#pragma unroll
    for (int kf = 0; kf < 2; kf++) {
      int ko = kf * 32 + quad * 8;
      bf16x8 a_h = *(const bf16x8*)&Ash[wr * 16 + l16][ko];
      bf16x8 a_l = *(const bf16x8*)&Asl[wr * 16 + l16][ko];
      bf16x8 w_h = *(const bf16x8*)&Wsh[wc * 16 + l16][ko];
      bf16x8 w_l = *(const bf16x8*)&Wsl[wc * 16 + l16][ko];
      acc = __builtin_amdgcn_mfma_f32_16x16x32_bf16(a_h, w_h, acc, 0, 0, 0);
      acc = __builtin_amdgcn_mfma_f32_16x16x32_bf16(a_h, w_l, acc, 0, 0, 0);
      acc = __builtin_amdgcn_mfma_f32_16x16x32_bf16(a_l, w_h, acc, 0, 0, 0);
    }
    __syncthreads();
  }
  int col = nb * 32 + wc * 16 + l16;
  int row0 = mb * 32 + wr * 16 + quad * 4;
#pragma unroll
  for (int r = 0; r < 4; r++)
    Z[(size_t)(row0 + r) * 512 + col] = acc[r];
}

// ---------------------------------------------------------------------------
// k_comb: next[r] = relu(Z1[r] + sum_{e in in(r)} Z2[src_e] + b).  2 waves
// per row split the edge list; LDS combine.  Writes states fp32 + bf16 split
// of next A (chunked layout).
// ---------------------------------------------------------------------------
__global__ __launch_bounds__(256) void k_comb(
    const float* __restrict__ Z, const float* __restrict__ bias,
    const int* __restrict__ row_ptr, const int* __restrict__ csr_src,
    float* __restrict__ stnext, ushort* __restrict__ NAh,
    ushort* __restrict__ NAl) {
  __shared__ float4 part[2][64];
  int wid = threadIdx.x >> 6, lane = threadIdx.x & 63;
  int rp = wid >> 1, half = wid & 1;
  int row = blockIdx.x * 2 + rp;
  int e0 = row_ptr[row], e1 = row_ptr[row + 1];
  int mid = (e0 + e1 + 1) >> 1;
  int lo = half ? mid : e0, hi = half ? e1 : mid;
  float4 acc = {0.f, 0.f, 0.f, 0.f};
  for (int e = lo; e < hi; e++) {
    const float4* z2 = (const float4*)(Z + (size_t)csr_src[e] * 512 + 256);
    float4 x = z2[lane];
    acc.x += x.x; acc.y += x.y; acc.z += x.z; acc.w += x.w;
  }
  if (half) part[rp][lane] = acc;
  __syncthreads();
  if (!half) {
    float4 o = part[rp][lane];
    float4 zs = ((const float4*)(Z + (size_t)row * 512))[lane];
    float4 bv = ((const float4*)bias)[lane];
    float v0 = fmaxf(acc.x + o.x + zs.x + bv.x, 0.f);
    float v1 = fmaxf(acc.y + o.y + zs.y + bv.y, 0.f);
    float v2 = fmaxf(acc.z + o.z + zs.z + bv.z, 0.f);
    float v3 = fmaxf(acc.w + o.w + zs.w + bv.w, 0.f);
    *(float4*)(stnext + (size_t)row * D + lane * 4) = make_float4(v0, v1, v2, v3);
    ushort h0 = bf16_rn(v0), h1 = bf16_rn(v1), h2 = bf16_rn(v2), h3 = bf16_rn(v3);
    size_t ca = a_addr(row, lane * 4);
    *(ushort4*)&NAh[ca] = make_ushort4(h0, h1, h2, h3);
    *(ushort4*)&NAl[ca] = make_ushort4(
        bf16_rn(v0 - bf16_f(h0)), bf16_rn(v1 - bf16_f(h1)),
        bf16_rn(v2 - bf16_f(h2)), bf16_rn(v3 - bf16_f(h3)));
  }
}

// ---------------------------------------------------------------------------
// k_pi: LINEAR reformulation (validated R5).  Per column c:
//   pref[e] = cat[e] + pref[prev(e)]
//   S_i = S_{i-1} + sum_{e in step i} pref[e] + sum_{j<i} cmat[i][j]*S_j
//   out[p] += pref[last(p)] + sum_{i in pmask(p)} S_i
// ---------------------------------------------------------------------------
#define PI_LDS_BYTES (TCAP * 64 * 4 + 16 * 64 * 4 + 3 * TCAP * 4 + 17 * 4 + 16 * 4 + 256 * 4)
__global__ __launch_bounds__(64) void k_pi(
    const float* __restrict__ states, float* __restrict__ out,
    const int* __restrict__ variants,
    const int* __restrict__ entP, const int* __restrict__ entPrev,
    const int* __restrict__ entDm, const int* __restrict__ offsG,
    const int* __restrict__ kidxG, const int* __restrict__ tlG,
    const int* __restrict__ cmatG, const int* __restrict__ lastPG,
    const int* __restrict__ lastIG, const int* __restrict__ lastMG,
    const int* __restrict__ cntG) {
  extern __shared__ __align__(16) float smf[];
  float* catb = smf;                       // [TCAP][64]  (becomes pref)
  float* S_lds = catb + TCAP * 64;         // [16][64]
  int* eP  = (int*)(S_lds + 16 * 64);      // [TCAP]
  int* ePr = eP + TCAP;
  int* eDm = ePr + TCAP;
  int* offs = eDm + TCAP;                  // [17]
  int* kidx = offs + 17;                   // [16]
  int* tl = kidx + 16;                     // [256]
  int v = blockIdx.x / 12, cgi = blockIdx.x % 12;
  int grp = cgi >> 2;
  int lane = threadIdx.x;
  int cl = (cgi & 3) * 64 + lane;          // 0..255 within third
  int col = cgi * 64 + lane;               // 0..767

  int T = cntG[v * 2 + 0], U = cntG[v * 2 + 1];
  for (int x = lane; x < T; x += 64) {
    eP[x] = entP[v * TCAP + x];
    ePr[x] = entPrev[v * TCAP + x];
    eDm[x] = entDm[v * TCAP + x];
  }
  for (int x = lane; x < 17; x += 64) offs[x] = offsG[v * 17 + x];
  if (lane < 16) kidx[lane] = kidxG[v * 16 + lane];
  for (int x = lane; x < 256; x += 64) tl[x] = tlG[v * 256 + x];
  __syncthreads();

  // Phase 1: gather cat values (independent loads)
  for (int i = 0; i < L; i++) {
    int kk = kidx[i]; if (kk > NSTATE - 1) kk = NSTATE - 1;
    const float* embS = states + (size_t)kk * N * D;
    int o0 = offs[i], o1 = offs[i + 1];
    if (grp == 0) {
      for (int e = o0; e < o1; e++)
        catb[e * 64 + lane] = embS[(size_t)eP[e] * D + cl];
    } else if (grp == 1) {
      float embA = embS[(size_t)variants[v * L + i] * D + cl];
      for (int e = o0; e < o1; e++) catb[e * 64 + lane] = embA;
    } else {
      for (int e = o0; e < o1; e++) {
        float s = 0.f;
        int b = eDm[e];
        while (b) {
          int q = __ffs(b) - 1; b &= b - 1;
          s += embS[(size_t)tl[i * 16 + q] * D + cl];
        }
        catb[e * 64 + lane] = s;
      }
    }
  }
  // Phase 2: in-place per-slot prefix (prev < e, ascending order)
  for (int e = 0; e < T; e++) {
    int pr = ePr[e];
    if (pr >= 0) catb[e * 64 + lane] += catb[pr * 64 + lane];
  }
  // Phase 3: 16-step S recurrence (registers)
  float S[16];
  float Sp = 0.f;
#pragma unroll
  for (int i = 0; i < 16; i++) {
    float a = 0.f;
    for (int e = offs[i]; e < offs[i + 1]; e++) a += catb[e * 64 + lane];
    float s = Sp + a;
#pragma unroll
    for (int j = 0; j < 16; j++)
      if (j < i) s += (float)cmatG[v * 256 + i * 16 + j] * S[j];
    S[i] = s;
    S_lds[i * 64 + lane] = s;
    Sp = s;
  }
  // Phase 4: one atomic per (union place, col)
  for (int u = 0; u < U; u++) {
    int p = lastPG[v * TCAP + u];
    int li = lastIG[v * TCAP + u];
    int m = lastMG[v * TCAP + u];
    float acc = catb[li * 64 + lane];
    while (m) {
      int q = __ffs(m) - 1; m &= m - 1;
      acc += S_lds[q * 64 + lane];
    }
    atomicAdd(&out[(size_t)p * C + col], acc);
  }
}

// ---------------------------------------------------------------------------
extern "C" void kernel_launch(void* const* d_in, const int* in_sizes, int n_in,
                              void* d_out, int out_size, void* d_ws, size_t ws_size,
                              hipStream_t stream) {
  const float* emb      = (const float*)d_in[0];
  const float* Ws       = (const float*)d_in[1];
  const float* Wn       = (const float*)d_in[2];
  const float* bias     = (const float*)d_in[3];
  const int*   variants = (const int*)d_in[4];
  const int*   adj      = (const int*)d_in[5];
  const int*   ei       = (const int*)d_in[6];
  const int    E        = in_sizes[6] / 2;
  float* out            = (float*)d_out;

  char* base = (char*)d_ws;
  float* states = (float*)base;            base += (size_t)NSTATE * N * D * 4;
  float* Z      = (float*)base;            base += (size_t)N * 512 * 4;
  ushort* WtHi  = (ushort*)base;           base += (size_t)512 * 256 * 2;
  ushort* WtLo  = (ushort*)base;           base += (size_t)512 * 256 * 2;
  ushort* A0h   = (ushort*)base;           base += (size_t)N * D * 2;
  ushort* A0l   = (ushort*)base;           base += (size_t)N * D * 2;
  ushort* A1h   = (ushort*)base;           base += (size_t)N * D * 2;
  ushort* A1l   = (ushort*)base;           base += (size_t)N * D * 2;
  int* row_ptr  = (int*)base;              base += (N + 1) * 4;
  int* fillpos  = (int*)base;              base += N * 4;
  int* csr_src  = (int*)base;              base += (size_t)E * 4;
  int* stepP    = (int*)base;              base += V * L * FCAP * 4;
  int* stepDm   = (int*)base;              base += V * L * FCAP * 4;
  int* stepCnt  = (int*)base;              base += V * L * 4;
  int* hasG     = (int*)base;              base += V * L * 4;
  int* entP     = (int*)base;              base += V * TCAP * 4;
  int* entPrev  = (int*)base;              base += V * TCAP * 4;
  int* entDm    = (int*)base;              base += V * TCAP * 4;
  int* offsG    = (int*)base;              base += V * 17 * 4;
  int* kidxG    = (int*)base;              base += V * 16 * 4;
  int* tlG      = (int*)base;              base += V * 256 * 4;
  int* cmatG    = (int*)base;              base += V * 256 * 4;
  int* lastPG   = (int*)base;              base += V * TCAP * 4;
  int* lastIG   = (int*)base;              base += V * TCAP * 4;
  int* lastMG   = (int*)base;              base += V * TCAP * 4;
  int* cntG     = (int*)base;              base += V * 2 * 4;

  hipFuncSetAttribute((const void*)k_pi,
                      hipFuncAttributeMaxDynamicSharedMemorySize, PI_LDS_BYTES);

  k_init<<<512, 256, 0, stream>>>(emb, Ws, Wn, states, WtHi, WtLo, A0h, A0l,
                                  out, fillpos);
  k_deg<<<(E + 255) / 256, 256, 0, stream>>>(ei, fillpos, E);
  k_scan<<<1, 256, 0, stream>>>(fillpos, row_ptr);
  k_fill<<<(E + 255) / 256, 256, 0, stream>>>(ei, fillpos, csr_src, E);
  k_metaA<<<V * L, 256, 0, stream>>>(adj, variants, stepP, stepDm, stepCnt,
                                     hasG, tlG);
  k_metaB<<<V, 256, 0, stream>>>(stepP, stepDm, stepCnt, hasG, entP, entPrev,
                                 entDm, offsG, kidxG, cmatG, lastPG, lastIG,
                                 lastMG, cntG);

  ushort* AH[2] = {A0h, A1h};
  ushort* AL[2] = {A0l, A1l};
  for (int s = 0; s < NAPP; s++) {
    int cur = s & 1, nxt = cur ^ 1;
    k_gemm<<<dim3(64, 16), 256, 0, stream>>>(AH[cur], AL[cur], WtHi, WtLo, Z);
    k_comb<<<N / 2, 256, 0, stream>>>(Z, bias, row_ptr, csr_src,
                                      states + (size_t)(s + 1) * N * D,
                                      AH[nxt], AL[nxt]);
  }
  k_pi<<<V * 12, 64, PI_LDS_BYTES, stream>>>(states, out, variants, entP,
                                             entPrev, entDm, offsG, kidxG, tlG,
                                             cmatG, lastPG, lastIG, lastMG, cntG);
}

// Round 7
// 379.982 us; speedup vs baseline: 1.2863x; 1.0181x over previous
//
#include <hip/hip_runtime.h>

// Problem constants (fixed by the reference)
#define N 2048
#define D 256
#define C 768          // 3*D
#define V 2
#define L 16
#define NSTATE 15      // S_0..S_14 (step-15 mask provably empty)
#define NAPP 14        // encoder applications
#define TCAP 256       // canonical masked-entry cap per variant (expected ~107)
#define FCAP 64        // follower cap per step (expected ~32)

typedef __attribute__((ext_vector_type(8))) short bf16x8;
typedef __attribute__((ext_vector_type(4))) float f32x4;

__device__ __forceinline__ ushort bf16_rn(float x) {
  unsigned u = __float_as_uint(x);
  u += 0x7FFFu + ((u >> 16) & 1u);
  return (ushort)(u >> 16);
}
__device__ __forceinline__ float bf16_f(ushort h) {
  return __uint_as_float(((unsigned)h) << 16);
}

// Chunk-tiled operand layouts (chunk = 32 rows x 64 k = 2048 ushorts = 4 KB).
__device__ __forceinline__ size_t a_addr(int row, int k) {
  return ((size_t)(row >> 5) * 4 + (k >> 6)) * 2048 + (row & 31) * 64 + (k & 63);
}
__device__ __forceinline__ size_t wt_addr(int n, int k) {
  return ((size_t)(n >> 5) * 4 + (k >> 6)) * 2048 + (n & 31) * 64 + (k & 63);
}

// ---------------------------------------------------------------------------
// k_init: states0 = emb; A0 bf16 split (chunked); Wt=[W_self|W_nbr]^T split
// (chunked); zero out / fillpos.
// ---------------------------------------------------------------------------
__global__ __launch_bounds__(256) void k_init(
    const float* __restrict__ emb, const float* __restrict__ Ws,
    const float* __restrict__ Wn, float* __restrict__ states0,
    ushort* __restrict__ WtHi, ushort* __restrict__ WtLo,
    ushort* __restrict__ A0hi, ushort* __restrict__ A0lo,
    float* __restrict__ out, int* __restrict__ fillpos) {
  size_t i = (size_t)blockIdx.x * 256 + threadIdx.x;
  size_t stride = (size_t)gridDim.x * 256;
  for (size_t x = i; x < (size_t)N * D; x += stride) {
    float v = emb[x];
    states0[x] = v;
    ushort h = bf16_rn(v);
    ushort l = bf16_rn(v - bf16_f(h));
    size_t a = a_addr((int)(x >> 8), (int)(x & 255));
    A0hi[a] = h;
    A0lo[a] = l;
  }
  for (size_t x = i; x < (size_t)512 * 256; x += stride) {
    int n = (int)(x >> 8), k = (int)(x & 255);
    float v = (n < 256) ? Ws[(size_t)k * 256 + n] : Wn[(size_t)k * 256 + (n - 256)];
    ushort h = bf16_rn(v);
    size_t a = wt_addr(n, k);
    WtHi[a] = h;
    WtLo[a] = bf16_rn(v - bf16_f(h));
  }
  for (size_t x = i; x < (size_t)N * C; x += stride) out[x] = 0.f;
  for (size_t x = i; x < N; x += stride) fillpos[x] = 0;
}

// ---------------------------------------------------------------------------
// k_degA: fused k_deg (blocks 0..127) + k_metaA (blocks 128..159).
// deg: CSR degree count.  metaA: per (variant, step) follower lists with
// destination bitmasks (the only adj-touching meta work; step-independent).
// ---------------------------------------------------------------------------
__global__ __launch_bounds__(256) void k_degA(
    const int* __restrict__ ei, int E, int* __restrict__ fillpos,
    const int* __restrict__ adj, const int* __restrict__ variants,
    int* __restrict__ stepP, int* __restrict__ stepDm,
    int* __restrict__ stepCnt, int* __restrict__ hasG, int* __restrict__ tlG) {
  __shared__ int tl_sh[16];
  __shared__ int foll[FCAP], fbits[FCAP];
  __shared__ int sh_tc, sh_fcnt, sh_ecnt;
  int t = threadIdx.x;
  if (blockIdx.x < 128) {
    for (int e = blockIdx.x * 256 + t; e < E; e += 128 * 256)
      atomicAdd(&fillpos[ei[E + e]], 1);
    return;
  }
  int vi = blockIdx.x - 128;
  int v = vi / L, i = vi % L;
  int a = variants[vi];
  if (t == 0) {
    int cnt = 0;
    for (int j = i + 1; j < L; j++) {
      int x = variants[v * L + j];
      bool dup = false;
      for (int q = 0; q < cnt; q++) if (tl_sh[q] == x) dup = true;
      if (!dup) tl_sh[cnt++] = x;
    }
    sh_tc = cnt;
    sh_fcnt = 0;
    sh_ecnt = 0;
    for (int q = 0; q < cnt; q++) tlG[vi * 16 + q] = tl_sh[q];
  }
  __syncthreads();
  for (int p = t; p < N; p += 256) {
    if (adj[(size_t)a * N + p] != 0) {
      int f = atomicAdd(&sh_fcnt, 1);
      if (f < FCAP) foll[f] = p;
    }
  }
  __syncthreads();
  int fc = sh_fcnt < FCAP ? sh_fcnt : FCAP;
  int tc = sh_tc;
  for (int x = t; x < fc; x += 256) fbits[x] = 0;
  __syncthreads();
  for (int x = t; x < fc * tc; x += 256) {
    int fi = x / tc, q = x - fi * tc;
    if (adj[(size_t)foll[fi] * N + tl_sh[q]] != 0) atomicOr(&fbits[fi], 1 << q);
  }
  __syncthreads();
  for (int fi = t; fi < fc; fi += 256) {
    int bits = fbits[fi];
    if (bits) {
      int e = atomicAdd(&sh_ecnt, 1);
      stepP[vi * FCAP + e] = foll[fi];
      stepDm[vi * FCAP + e] = bits;
    }
  }
  __syncthreads();
  if (t == 0) {
    stepCnt[vi] = sh_ecnt;
    hasG[vi] = (sh_fcnt > 0);
  }
}

// ---------------------------------------------------------------------------
// k_scan: exclusive prefix over degrees -> row_ptr; resets fillpos to starts.
// ---------------------------------------------------------------------------
__global__ __launch_bounds__(256) void k_scan(int* __restrict__ fillpos,
                                              int* __restrict__ row_ptr) {
  __shared__ int part[256];
  __shared__ int base[257];
  int t = threadIdx.x;
  int v[8];
  int s = 0;
  for (int j = 0; j < 8; j++) { v[j] = fillpos[t * 8 + j]; s += v[j]; }
  part[t] = s;
  __syncthreads();
  if (t == 0) {
    int acc = 0;
    for (int q = 0; q < 256; q++) { base[q] = acc; acc += part[q]; }
    base[256] = acc;
  }
  __syncthreads();
  int acc = base[t];
  for (int j = 0; j < 8; j++) {
    row_ptr[t * 8 + j] = acc;
    fillpos[t * 8 + j] = acc;
    acc += v[j];
  }
  if (t == 255) row_ptr[N] = base[256];
}

// ---------------------------------------------------------------------------
// k_fillB: fused k_fill (blocks 0..127) + k_metaB (blocks 128..128+V-1).
// metaB: per-variant linking on compacted lists (entP/entPrev/entDm + offs,
// kidx, last-entry lists, cmat).  No adj access.
// ---------------------------------------------------------------------------
__global__ __launch_bounds__(256) void k_fillB(
    const int* __restrict__ ei, int E, int* __restrict__ fillpos,
    int* __restrict__ csr_src,
    const int* __restrict__ stepP, const int* __restrict__ stepDm,
    const int* __restrict__ stepCnt, const int* __restrict__ hasG,
    int* __restrict__ entP, int* __restrict__ entPrev, int* __restrict__ entDm,
    int* __restrict__ offsG, int* __restrict__ kidxG, int* __restrict__ cmatG,
    int* __restrict__ lastPG, int* __restrict__ lastIG, int* __restrict__ lastMG,
    int* __restrict__ cntG) {
  __shared__ int pmask[N];           // 8 KB
  __shared__ int sP[16][FCAP];       // 4 KB
  __shared__ int sDm[16][FCAP];      // 4 KB
  __shared__ int cnt[16], offs[17];
  __shared__ int cmat_sh[256];       // 1 KB
  __shared__ int sh_u;
  int t = threadIdx.x;
  if (blockIdx.x < 128) {
    for (int e = blockIdx.x * 256 + t; e < E; e += 128 * 256) {
      int dst = ei[E + e];
      int pos = atomicAdd(&fillpos[dst], 1);
      csr_src[pos] = ei[e];
    }
    return;
  }
  int v = blockIdx.x - 128;
  for (int p = t; p < N; p += 256) pmask[p] = 0;
  for (int x = t; x < 256; x += 256) cmat_sh[x] = 0;
  if (t < 16) cnt[t] = stepCnt[v * L + t];
  if (t == 0) sh_u = 0;
  __syncthreads();
  if (t == 0) {
    int acc = 0;
    for (int i = 0; i < 16; i++) {
      offs[i] = acc < TCAP ? acc : TCAP;
      acc += cnt[i];
    }
    offs[16] = acc < TCAP ? acc : TCAP;
    cntG[v * 2 + 0] = offs[16];
    int k = 0;
    for (int i = 0; i < L; i++) {
      kidxG[v * 16 + i] = k;
      if (hasG[v * L + i]) k++;
    }
  }
  for (int x = t; x < 16 * FCAP; x += 256) {
    int i = x >> 6, f = x & 63;
    if (f < stepCnt[v * L + i]) {
      int p = stepP[(v * L + i) * FCAP + f];
      sP[i][f] = p;
      sDm[i][f] = stepDm[(v * L + i) * FCAP + f];
      atomicOr(&pmask[p], 1 << i);
    }
  }
  __syncthreads();
  for (int x = t; x < 16 * FCAP; x += 256) {
    int i = x >> 6, f = x & 63;
    if (f < cnt[i]) {
      int e = offs[i] + f;
      if (e < TCAP) {
        int p = sP[i][f];
        entP[v * TCAP + e] = p;
        entDm[v * TCAP + e] = sDm[i][f];
        int m = pmask[p] & ((1 << i) - 1);
        int prev = -1;
        if (m) {
          int j = 31 - __clz(m);
          int cj = cnt[j];
          for (int f2 = 0; f2 < cj; f2++)
            if (sP[j][f2] == p) { prev = offs[j] + f2; break; }
        }
        entPrev[v * TCAP + e] = prev;
      }
    }
  }
  __syncthreads();
  for (int p = t; p < N; p += 256) {
    int m = pmask[p];
    if (m) {
      int u = atomicAdd(&sh_u, 1);
      int j = 31 - __clz(m);
      int li = -1;
      int cj = cnt[j];
      for (int f2 = 0; f2 < cj; f2++)
        if (sP[j][f2] == p) { li = offs[j] + f2; break; }
      lastPG[v * TCAP + u] = p;
      lastIG[v * TCAP + u] = li;
      lastMG[v * TCAP + u] = m;
      int mm = m;
      while (mm) {
        int bi = __ffs(mm) - 1; mm &= mm - 1;
        int m2 = m & ((1 << bi) - 1);
        while (m2) {
          int bj = __ffs(m2) - 1; m2 &= m2 - 1;
          atomicAdd(&cmat_sh[bi * 16 + bj], 1);
        }
      }
    }
  }
  __syncthreads();
  if (t == 0) cntG[v * 2 + 1] = sh_u;
  for (int x = t; x < 256; x += 256) cmatG[v * 256 + x] = cmat_sh[x];
  for (int x = t; x < 17; x += 256) offsG[v * 17 + x] = offs[x];
}

// ---------------------------------------------------------------------------
// k_gemm: Z = A @ [W_self|W_nbr]  (M=2048, K=256, N=512), bf16 3-product
// split, fp32 accum.  LDS double-buffered: 4 __syncthreads total (was 8);
// global prefetch of chunk c+1 overlaps MFMA of chunk c.
// ---------------------------------------------------------------------------
__global__ __launch_bounds__(256) void k_gemm(
    const ushort* __restrict__ Ah, const ushort* __restrict__ Al,
    const ushort* __restrict__ Wh_g, const ushort* __restrict__ Wl_g,
    float* __restrict__ Z) {
  __shared__ __align__(16) ushort Ash[2][32][72], Asl[2][32][72];
  __shared__ __align__(16) ushort Wsh[2][32][72], Wsl[2][32][72];
  const int tid = threadIdx.x, wave = tid >> 6, lane = tid & 63;
  const int quad = lane >> 4, l16 = lane & 15;
  const int wr = wave >> 1, wc = wave & 1;
  const int mb = blockIdx.x, nb = blockIdx.y;
  const int sr = tid >> 3, sc = (tid & 7) * 8;

  f32x4 acc = {0.f, 0.f, 0.f, 0.f};
  size_t abase = (size_t)mb * 4 * 2048 + (size_t)tid * 8;
  size_t wbase = (size_t)nb * 4 * 2048 + (size_t)tid * 8;
  // stage chunk 0 into buf 0
  {
    uint4 ra  = *(const uint4*)&Ah[abase];
    uint4 rl  = *(const uint4*)&Al[abase];
    uint4 rwh = *(const uint4*)&Wh_g[wbase];
    uint4 rwl = *(const uint4*)&Wl_g[wbase];
    *(uint4*)&Ash[0][sr][sc] = ra;
    *(uint4*)&Asl[0][sr][sc] = rl;
    *(uint4*)&Wsh[0][sr][sc] = rwh;
    *(uint4*)&Wsl[0][sr][sc] = rwl;
  }
  __syncthreads();
#pragma unroll
  for (int c = 0; c < 4; c++) {
    const int rb = c & 1;
    uint4 ra, rl, rwh, rwl;
    if (c < 3) {
      size_t o = (size_t)(c + 1) * 2048;
      ra  = *(const uint4*)&Ah[abase + o];
      rl  = *(const uint4*)&Al[abase + o];
      rwh = *(const uint4*)&Wh_g[wbase + o];
      rwl = *(const uint4*)&Wl_g[wbase + o];
    }
#pragma unroll
    for (int kf = 0; kf < 2; kf++) {
      int ko = kf * 32 + quad * 8;
      bf16x8 a_h = *(const bf16x8*)&Ash[rb][wr * 16 + l16][ko];
      bf16x8 a_l = *(const bf16x8*)&Asl[rb][wr * 16 + l16][ko];
      bf16x8 w_h = *(const bf16x8*)&Wsh[rb][wc * 16 + l16][ko];
      bf16x8 w_l = *(const bf16x8*)&Wsl[rb][wc * 16 + l16][ko];
      acc = __builtin_amdgcn_mfma_f32_16x16x32_bf16(a_h, w_h, acc, 0, 0, 0);
      acc = __builtin_amdgcn_mfma_f32_16x16x32_bf16(a_h, w_l, acc, 0, 0, 0);
      acc = __builtin_amdgcn_mfma_f32_16x16x32_bf16(a_l, w_h, acc, 0, 0, 0);
    }
    if (c < 3) {
      const int wb = rb ^ 1;
      *(uint4*)&Ash[wb][sr][sc] = ra;
      *(uint4*)&Asl[wb][sr][sc] = rl;
      *(uint4*)&Wsh[wb][sr][sc] = rwh;
      *(uint4*)&Wsl[wb][sr][sc] = rwl;
      __syncthreads();
    }
  }
  int col = nb * 32 + wc * 16 + l16;
  int row0 = mb * 32 + wr * 16 + quad * 4;
#pragma unroll
  for (int r = 0; r < 4; r++)
    Z[(size_t)(row0 + r) * 512 + col] = acc[r];
}

// ---------------------------------------------------------------------------
// k_comb: next[r] = relu(Z1[r] + sum_{e in in(r)} Z2[src_e] + b).
// One wave per row (no LDS, no sync), 2-way unrolled gather (2 accumulators,
// 2 loads in flight).  Writes states fp32 + bf16 split of next A (chunked).
// ---------------------------------------------------------------------------
__global__ __launch_bounds__(256) void k_comb(
    const float* __restrict__ Z, const float* __restrict__ bias,
    const int* __restrict__ row_ptr, const int* __restrict__ csr_src,
    float* __restrict__ stnext, ushort* __restrict__ NAh,
    ushort* __restrict__ NAl) {
  int row = blockIdx.x * 4 + (threadIdx.x >> 6);
  int lane = threadIdx.x & 63;
  const float4* Zp = (const float4*)Z;
  float4 acc = Zp[(size_t)row * 128 + lane];            // Z1 self
  float4 acc2 = {0.f, 0.f, 0.f, 0.f};
  int e0 = row_ptr[row], e1 = row_ptr[row + 1];
  int e = e0;
  for (; e + 1 < e1; e += 2) {
    int s0 = csr_src[e], s1 = csr_src[e + 1];
    float4 x0 = Zp[(size_t)s0 * 128 + 64 + lane];
    float4 x1 = Zp[(size_t)s1 * 128 + 64 + lane];
    acc.x += x0.x; acc.y += x0.y; acc.z += x0.z; acc.w += x0.w;
    acc2.x += x1.x; acc2.y += x1.y; acc2.z += x1.z; acc2.w += x1.w;
  }
  if (e < e1) {
    float4 x0 = Zp[(size_t)csr_src[e] * 128 + 64 + lane];
    acc.x += x0.x; acc.y += x0.y; acc.z += x0.z; acc.w += x0.w;
  }
  float4 bv = ((const float4*)bias)[lane];
  float v0 = fmaxf(acc.x + acc2.x + bv.x, 0.f);
  float v1 = fmaxf(acc.y + acc2.y + bv.y, 0.f);
  float v2 = fmaxf(acc.z + acc2.z + bv.z, 0.f);
  float v3 = fmaxf(acc.w + acc2.w + bv.w, 0.f);
  *(float4*)(stnext + (size_t)row * D + lane * 4) = make_float4(v0, v1, v2, v3);
  ushort h0 = bf16_rn(v0), h1 = bf16_rn(v1), h2 = bf16_rn(v2), h3 = bf16_rn(v3);
  size_t ca = a_addr(row, lane * 4);
  *(ushort4*)&NAh[ca] = make_ushort4(h0, h1, h2, h3);
  *(ushort4*)&NAl[ca] = make_ushort4(
      bf16_rn(v0 - bf16_f(h0)), bf16_rn(v1 - bf16_f(h1)),
      bf16_rn(v2 - bf16_f(h2)), bf16_rn(v3 - bf16_f(h3)));
}

// ---------------------------------------------------------------------------
// k_pi: LINEAR reformulation (validated R5/R6).  Per column c:
//   pref[e] = cat[e] + pref[prev(e)]
//   S_i = S_{i-1} + sum_{e in step i} pref[e] + sum_{j<i} cmat[i][j]*S_j
//   out[p] += pref[last(p)] + sum_{i in pmask(p)} S_i
// ---------------------------------------------------------------------------
#define PI_LDS_BYTES (TCAP * 64 * 4 + 16 * 64 * 4 + 3 * TCAP * 4 + 17 * 4 + 16 * 4 + 256 * 4)
__global__ __launch_bounds__(64) void k_pi(
    const float* __restrict__ states, float* __restrict__ out,
    const int* __restrict__ variants,
    const int* __restrict__ entP, const int* __restrict__ entPrev,
    const int* __restrict__ entDm, const int* __restrict__ offsG,
    const int* __restrict__ kidxG, const int* __restrict__ tlG,
    const int* __restrict__ cmatG, const int* __restrict__ lastPG,
    const int* __restrict__ lastIG, const int* __restrict__ lastMG,
    const int* __restrict__ cntG) {
  extern __shared__ __align__(16) float smf[];
  float* catb = smf;                       // [TCAP][64]  (becomes pref)
  float* S_lds = catb + TCAP * 64;         // [16][64]
  int* eP  = (int*)(S_lds + 16 * 64);      // [TCAP]
  int* ePr = eP + TCAP;
  int* eDm = ePr + TCAP;
  int* offs = eDm + TCAP;                  // [17]
  int* kidx = offs + 17;                   // [16]
  int* tl = kidx + 16;                     // [256]
  int v = blockIdx.x / 12, cgi = blockIdx.x % 12;
  int grp = cgi >> 2;
  int lane = threadIdx.x;
  int cl = (cgi & 3) * 64 + lane;          // 0..255 within third
  int col = cgi * 64 + lane;               // 0..767

  int T = cntG[v * 2 + 0], U = cntG[v * 2 + 1];
  for (int x = lane; x < T; x += 64) {
    eP[x] = entP[v * TCAP + x];
    ePr[x] = entPrev[v * TCAP + x];
    eDm[x] = entDm[v * TCAP + x];
  }
  for (int x = lane; x < 17; x += 64) offs[x] = offsG[v * 17 + x];
  if (lane < 16) kidx[lane] = kidxG[v * 16 + lane];
  for (int x = lane; x < 256; x += 64) tl[x] = tlG[v * 256 + x];
  __syncthreads();

  for (int i = 0; i < L; i++) {
    int kk = kidx[i]; if (kk > NSTATE - 1) kk = NSTATE - 1;
    const float* embS = states + (size_t)kk * N * D;
    int o0 = offs[i], o1 = offs[i + 1];
    if (grp == 0) {
      for (int e = o0; e < o1; e++)
        catb[e * 64 + lane] = embS[(size_t)eP[e] * D + cl];
    } else if (grp == 1) {
      float embA = embS[(size_t)variants[v * L + i] * D + cl];
      for (int e = o0; e < o1; e++) catb[e * 64 + lane] = embA;
    } else {
      for (int e = o0; e < o1; e++) {
        float s = 0.f;
        int b = eDm[e];
        while (b) {
          int q = __ffs(b) - 1; b &= b - 1;
          s += embS[(size_t)tl[i * 16 + q] * D + cl];
        }
        catb[e * 64 + lane] = s;
      }
    }
  }
  for (int e = 0; e < T; e++) {
    int pr = ePr[e];
    if (pr >= 0) catb[e * 64 + lane] += catb[pr * 64 + lane];
  }
  float S[16];
  float Sp = 0.f;
#pragma unroll
  for (int i = 0; i < 16; i++) {
    float a = 0.f;
    for (int e = offs[i]; e < offs[i + 1]; e++) a += catb[e * 64 + lane];
    float s = Sp + a;
#pragma unroll
    for (int j = 0; j < 16; j++)
      if (j < i) s += (float)cmatG[v * 256 + i * 16 + j] * S[j];
    S[i] = s;
    S_lds[i * 64 + lane] = s;
    Sp = s;
  }
  for (int u = 0; u < U; u++) {
    int p = lastPG[v * TCAP + u];
    int li = lastIG[v * TCAP + u];
    int m = lastMG[v * TCAP + u];
    float acc = catb[li * 64 + lane];
    while (m) {
      int q = __ffs(m) - 1; m &= m - 1;
      acc += S_lds[q * 64 + lane];
    }
    atomicAdd(&out[(size_t)p * C + col], acc);
  }
}

// ---------------------------------------------------------------------------
extern "C" void kernel_launch(void* const* d_in, const int* in_sizes, int n_in,
                              void* d_out, int out_size, void* d_ws, size_t ws_size,
                              hipStream_t stream) {
  const float* emb      = (const float*)d_in[0];
  const float* Ws       = (const float*)d_in[1];
  const float* Wn       = (const float*)d_in[2];
  const float* bias     = (const float*)d_in[3];
  const int*   variants = (const int*)d_in[4];
  const int*   adj      = (const int*)d_in[5];
  const int*   ei       = (const int*)d_in[6];
  const int    E        = in_sizes[6] / 2;
  float* out            = (float*)d_out;

  char* base = (char*)d_ws;
  float* states = (float*)base;            base += (size_t)NSTATE * N * D * 4;
  float* Z      = (float*)base;            base += (size_t)N * 512 * 4;
  ushort* WtHi  = (ushort*)base;           base += (size_t)512 * 256 * 2;
  ushort* WtLo  = (ushort*)base;           base += (size_t)512 * 256 * 2;
  ushort* A0h   = (ushort*)base;           base += (size_t)N * D * 2;
  ushort* A0l   = (ushort*)base;           base += (size_t)N * D * 2;
  ushort* A1h   = (ushort*)base;           base += (size_t)N * D * 2;
  ushort* A1l   = (ushort*)base;           base += (size_t)N * D * 2;
  int* row_ptr  = (int*)base;              base += (N + 1) * 4;
  int* fillpos  = (int*)base;              base += N * 4;
  int* csr_src  = (int*)base;              base += (size_t)E * 4;
  int* stepP    = (int*)base;              base += V * L * FCAP * 4;
  int* stepDm   = (int*)base;              base += V * L * FCAP * 4;
  int* stepCnt  = (int*)base;              base += V * L * 4;
  int* hasG     = (int*)base;              base += V * L * 4;
  int* entP     = (int*)base;              base += V * TCAP * 4;
  int* entPrev  = (int*)base;              base += V * TCAP * 4;
  int* entDm    = (int*)base;              base += V * TCAP * 4;
  int* offsG    = (int*)base;              base += V * 17 * 4;
  int* kidxG    = (int*)base;              base += V * 16 * 4;
  int* tlG      = (int*)base;              base += V * 256 * 4;
  int* cmatG    = (int*)base;              base += V * 256 * 4;
  int* lastPG   = (int*)base;              base += V * TCAP * 4;
  int* lastIG   = (int*)base;              base += V * TCAP * 4;
  int* lastMG   = (int*)base;              base += V * TCAP * 4;
  int* cntG     = (int*)base;              base += V * 2 * 4;

  hipFuncSetAttribute((const void*)k_pi,
                      hipFuncAttributeMaxDynamicSharedMemorySize, PI_LDS_BYTES);

  k_init<<<512, 256, 0, stream>>>(emb, Ws, Wn, states, WtHi, WtLo, A0h, A0l,
                                  out, fillpos);
  k_degA<<<128 + V * L, 256, 0, stream>>>(ei, E, fillpos, adj, variants,
                                          stepP, stepDm, stepCnt, hasG, tlG);
  k_scan<<<1, 256, 0, stream>>>(fillpos, row_ptr);
  k_fillB<<<128 + V, 256, 0, stream>>>(ei, E, fillpos, csr_src, stepP, stepDm,
                                       stepCnt, hasG, entP, entPrev, entDm,
                                       offsG, kidxG, cmatG, lastPG, lastIG,
                                       lastMG, cntG);

  ushort* AH[2] = {A0h, A1h};
  ushort* AL[2] = {A0l, A1l};
  for (int s = 0; s < NAPP; s++) {
    int cur = s & 1, nxt = cur ^ 1;
    k_gemm<<<dim3(64, 16), 256, 0, stream>>>(AH[cur], AL[cur], WtHi, WtLo, Z);
    k_comb<<<N / 4, 256, 0, stream>>>(Z, bias, row_ptr, csr_src,
                                      states + (size_t)(s + 1) * N * D,
                                      AH[nxt], AL[nxt]);
  }
  k_pi<<<V * 12, 64, PI_LDS_BYTES, stream>>>(states, out, variants, entP,
                                             entPrev, entDm, offsG, kidxG, tlG,
                                             cmatG, lastPG, lastIG, lastMG, cntG);
}